// Round 6
// baseline (127.206 us; speedup 1.0000x reference)
//
#include <hip/hip_runtime.h>

// Fused capsule conv + dynamic routing, dual-layout MFMA version.
// x:      [8, 32, 8, 32, 32] f32   (bs, ci, ni, hi, wi)
// conv_w: [256, 8, 3, 3]     f32   (co*no, ni, kh, kw)
// bias:   [32, 8, 1, 1]      f32
// out:    [8, 32, 8, 32, 32] f32   (bs, co, no, ho, wo)
//
// One block per pixel, 4 waves, wave owns 64 cols. Per-pixel GEMM
// votes[32ci][256col] via mfma_f32_16x16x32_bf16, 2-term truncating bf16
// split. Votes computed in BOTH orientations (operand swap, same frags):
//   acc [m][j]: D[ci][col]  ci = m*16+grp*4+r, col = wv*64+j*16+lc
//       -> preact ci-reduce = xor16/32 (cheap)
//   accT[j][m]: D[col][ci]  col = wv*64+j*16+grp*4+r, ci = m*16+lc
//       -> distance no-reduce = register r-sum + one xor16 (cheap)
// act redistributed acc->accT alignment via wave-private act_lds (no barrier).

typedef __attribute__((ext_vector_type(8))) short short8;
typedef __attribute__((ext_vector_type(4))) float f32x4;

#define LSTR 200   // A' row stride (ushort): 400 B
#define RSTR 36    // routeT row stride (f32)

__device__ __forceinline__ float bf2f(ushort h) {
    return __uint_as_float(((unsigned)h) << 16);
}
__device__ __forceinline__ ushort f2bf_rne(float f) {
    unsigned u = __float_as_uint(f);
    unsigned r = (u + 0x7fffu + ((u >> 16) & 1u)) >> 16;
    return (ushort)r;
}

__global__ void prep_w(const float* __restrict__ cw, ushort* __restrict__ wp) {
    int e = blockIdx.x * 256 + threadIdx.x;   // [col=256][k=96]
    int col = e / 96, k = e - col * 96;
    float v = (k < 72) ? cw[col * 72 + k] : 0.0f;
    wp[e] = f2bf_rne(v);
}

__global__ __launch_bounds__(256, 4)
void caps_mfma(const float* __restrict__ x,
               const ushort* __restrict__ wp,
               const float* __restrict__ bias,
               float* __restrict__ out)
{
    __shared__ ushort A[32 * LSTR];       // 12,800 B
    __shared__ float  logits[32 * 33];    //  4,224 B  [ci][co]
    __shared__ float  routeT[32 * RSTR];  //  4,608 B  [co][ci]
    __shared__ float  act_lds[256];       //  1,024 B  [col] (wave-private slices)

    const int t   = threadIdx.x;
    const int bid = blockIdx.x;
    const int b   = bid >> 10;
    const int hw  = bid & 1023;
    const int h   = hw >> 5;
    const int w   = hw & 31;

    // ---- stage A' rows: thread t <-> (ci = t>>3, ni = t&7); truncating split
    {
        const int ci = t >> 3, ni = t & 7;
        const float* xb = x + (((size_t)((b * 32 + ci) * 8 + ni)) << 10);
        ushort* Ar = A + ci * LSTR;
        #pragma unroll
        for (int kh = 0; kh < 3; ++kh)
            #pragma unroll
            for (int kw = 0; kw < 3; ++kw) {
                int hy = h + kh - 1, wx = w + kw - 1;   // block-uniform bounds
                float v = 0.0f;
                if ((unsigned)hy < 32u && (unsigned)wx < 32u) v = xb[(hy << 5) + wx];
                unsigned u = __float_as_uint(v);
                ushort hi = (ushort)(u >> 16);          // trunc: exact split in f32
                float lo = v - bf2f(hi);
                int k = ni * 9 + kh * 3 + kw;
                Ar[k]      = hi;
                Ar[96 + k] = (ushort)(__float_as_uint(lo) >> 16);
            }
        if (ni < 6) {   // zero K-pads 72..95 and 168..191
            uint2 z; z.x = 0u; z.y = 0u;
            *reinterpret_cast<uint2*>(Ar + 72  + ni * 4) = z;
            *reinterpret_cast<uint2*>(Ar + 168 + ni * 4) = z;
        }
    }
    __syncthreads();

    const int lane = t & 63, wv = t >> 6;
    const int lc = lane & 15, grp = lane >> 4;

    // ---- conv GEMM both orientations: 3 k-steps x {hi, lo}
    f32x4 acc[2][4];    // [m(ci-tile)][j(col-tile)]  D[ci][col]
    f32x4 accT[4][2];   // [j(col-tile)][m(ci-tile)]  D[col][ci]
    #pragma unroll
    for (int m = 0; m < 2; ++m)
        #pragma unroll
        for (int j = 0; j < 4; ++j) {
            acc[m][j]  = (f32x4){0.f, 0.f, 0.f, 0.f};
            accT[j][m] = (f32x4){0.f, 0.f, 0.f, 0.f};
        }

    #pragma unroll
    for (int ks = 0; ks < 3; ++ks) {
        short8 bq[4];
        #pragma unroll
        for (int j = 0; j < 4; ++j) {
            int col = wv * 64 + j * 16 + lc;
            bq[j] = *reinterpret_cast<const short8*>(wp + col * 96 + ks * 32 + grp * 8);
        }
        short8 ah[2], al[2];
        #pragma unroll
        for (int m = 0; m < 2; ++m) {
            const ushort* ar = A + (m * 16 + lc) * LSTR + ks * 32 + grp * 8;
            ah[m] = *reinterpret_cast<const short8*>(ar);
            al[m] = *reinterpret_cast<const short8*>(ar + 96);
        }
        #pragma unroll
        for (int m = 0; m < 2; ++m)
            #pragma unroll
            for (int j = 0; j < 4; ++j) {
                acc[m][j]  = __builtin_amdgcn_mfma_f32_16x16x32_bf16(ah[m], bq[j], acc[m][j], 0, 0, 0);
                acc[m][j]  = __builtin_amdgcn_mfma_f32_16x16x32_bf16(al[m], bq[j], acc[m][j], 0, 0, 0);
                accT[j][m] = __builtin_amdgcn_mfma_f32_16x16x32_bf16(bq[j], ah[m], accT[j][m], 0, 0, 0);
                accT[j][m] = __builtin_amdgcn_mfma_f32_16x16x32_bf16(bq[j], al[m], accT[j][m], 0, 0, 0);
            }
    }
    // no barrier: A-LDS read-only from here; routing uses other buffers

    float bj[4];
    #pragma unroll
    for (int j = 0; j < 4; ++j) bj[j] = bias[wv * 64 + j * 16 + lc];

    const int ci_s = t >> 3, j_s = t & 7;
    float act_[4];

    // ================= iteration 0: route = 1/32 exactly =================
    #pragma unroll
    for (int j = 0; j < 4; ++j) {
        float p = acc[0][j][0] + acc[0][j][1] + acc[0][j][2] + acc[0][j][3]
                + acc[1][j][0] + acc[1][j][1] + acc[1][j][2] + acc[1][j][3];
        p += __shfl_xor(p, 16);
        p += __shfl_xor(p, 32);             // sum over 32 ci, all lanes
        p = p * 0.03125f + bj[j];
        float s2 = p * p;
        s2 += __shfl_xor(s2, 1);
        s2 += __shfl_xor(s2, 2);
        s2 += __shfl_xor(s2, 4);            // sum over no
        act_[j] = p * sqrtf(s2) / (1.0f + s2);
    }

    // ---- distances via accT (it0: pure write of all 1024 logits)
    #pragma unroll
    for (int it = 0; it < 2; ++it) {        // placeholder structure below
        break;
    }

    {
        if (grp == 0) {
            #pragma unroll
            for (int j = 0; j < 4; ++j) act_lds[wv * 64 + j * 16 + lc] = act_[j];
        }
        #pragma unroll
        for (int j = 0; j < 4; ++j) {
            f32x4 a4 = *reinterpret_cast<const f32x4*>(act_lds + wv * 64 + j * 16 + grp * 4);
            #pragma unroll
            for (int m = 0; m < 2; ++m) {
                float d = accT[j][m][0] * a4[0] + accT[j][m][1] * a4[1]
                        + accT[j][m][2] * a4[2] + accT[j][m][3] * a4[3];
                d += __shfl_xor(d, 16);     // combine no 0..3 with 4..7
                if ((grp & 1) == 0) {
                    int ci = m * 16 + lc;
                    int co = wv * 8 + 2 * j + (grp >> 1);
                    logits[ci * 33 + co] = d;
                }
            }
        }
    }
    __syncthreads();

    // ================= iterations 1 and 2 =================
    for (int it = 1; it <= 2; ++it) {
        // (a) softmax over co; store transposed routeT[co][ci]
        float l0 = logits[ci_s * 33 + j_s];
        float l1 = logits[ci_s * 33 + j_s + 8];
        float l2 = logits[ci_s * 33 + j_s + 16];
        float l3 = logits[ci_s * 33 + j_s + 24];
        float mx = fmaxf(fmaxf(l0, l1), fmaxf(l2, l3));
        mx = fmaxf(mx, __shfl_xor(mx, 1));
        mx = fmaxf(mx, __shfl_xor(mx, 2));
        mx = fmaxf(mx, __shfl_xor(mx, 4));
        float e0 = __expf(l0 - mx), e1 = __expf(l1 - mx);
        float e2 = __expf(l2 - mx), e3 = __expf(l3 - mx);
        float s = e0 + e1 + e2 + e3;
        s += __shfl_xor(s, 1); s += __shfl_xor(s, 2); s += __shfl_xor(s, 4);
        float inv = 1.0f / s;
        routeT[(j_s)      * RSTR + ci_s] = e0 * inv;
        routeT[(j_s + 8)  * RSTR + ci_s] = e1 * inv;
        routeT[(j_s + 16) * RSTR + ci_s] = e2 * inv;
        routeT[(j_s + 24) * RSTR + ci_s] = e3 * inv;
        __syncthreads();

        // (b) preactivate (ci-reduce xor16/32) + squash (no-reduce xor1/2/4)
        const int par = (lane >> 3) & 1;
        #pragma unroll
        for (int j = 0; j < 4; ++j) {
            int co = (wv << 3) + 2 * j + par;
            f32x4 r0 = *reinterpret_cast<const f32x4*>(routeT + co * RSTR + grp * 4);
            f32x4 r1 = *reinterpret_cast<const f32x4*>(routeT + co * RSTR + 16 + grp * 4);
            float p = 0.0f;
            #pragma unroll
            for (int r = 0; r < 4; ++r) p = fmaf(r0[r], acc[0][j][r], p);
            #pragma unroll
            for (int r = 0; r < 4; ++r) p = fmaf(r1[r], acc[1][j][r], p);
            p += __shfl_xor(p, 16);
            p += __shfl_xor(p, 32);
            p += bj[j];
            float s2 = p * p;
            s2 += __shfl_xor(s2, 1);
            s2 += __shfl_xor(s2, 2);
            s2 += __shfl_xor(s2, 4);
            act_[j] = p * sqrtf(s2) / (1.0f + s2);
        }
        if (it == 2) break;

        // (c) distances via accT, accumulate into logits
        if (grp == 0) {
            #pragma unroll
            for (int j = 0; j < 4; ++j) act_lds[wv * 64 + j * 16 + lc] = act_[j];
        }
        #pragma unroll
        for (int j = 0; j < 4; ++j) {
            f32x4 a4 = *reinterpret_cast<const f32x4*>(act_lds + wv * 64 + j * 16 + grp * 4);
            #pragma unroll
            for (int m = 0; m < 2; ++m) {
                float d = accT[j][m][0] * a4[0] + accT[j][m][1] * a4[1]
                        + accT[j][m][2] * a4[2] + accT[j][m][3] * a4[3];
                d += __shfl_xor(d, 16);
                if ((grp & 1) == 0) {
                    int ci = m * 16 + lc;
                    int co = wv * 8 + 2 * j + (grp >> 1);
                    logits[ci * 33 + co] += d;
                }
            }
        }
        __syncthreads();
    }

    // ---- output: act_ replicated over grp; grp 0 writes the wave's 64 cols
    if (grp == 0) {
        #pragma unroll
        for (int j = 0; j < 4; ++j) {
            int col = wv * 64 + j * 16 + lc;
            out[(((size_t)(b << 8) + col) << 10) + hw] = act_[j];
        }
    }
}

extern "C" void kernel_launch(void* const* d_in, const int* in_sizes, int n_in,
                              void* d_out, int out_size, void* d_ws, size_t ws_size,
                              hipStream_t stream) {
    const float* x    = (const float*)d_in[0];
    const float* cw   = (const float*)d_in[1];
    const float* bias = (const float*)d_in[2];
    float* out = (float*)d_out;
    ushort* wp = (ushort*)d_ws;           // 256*96*2 = 49,152 B
    (void)in_sizes; (void)n_in; (void)out_size; (void)ws_size;
    prep_w<<<96, 256, 0, stream>>>(cw, wp);
    caps_mfma<<<8192, 256, 0, stream>>>(x, wp, bias, out);
}